// Round 12
// baseline (752.060 us; speedup 1.0000x reference)
//
#include <hip/hip_runtime.h>

#define U_N 100000
#define I_N 50000
#define D_N 128
#define B_N 4
#define E_N 500000
#define NEDGE (B_N * E_N)            // 2,000,000
#define NKEYU (4 * U_N)              // keys u*4+b
#define NKEYS (NKEYU + 4 * I_N)      // 600,000
#define NMEMB (2 * NEDGE)            // 4,000,000
#define SCHUNK 2048
#define SNBLK ((NKEYS + SCHUNK - 1) / SCHUNK)   // 293
#define TBI ((I_N + 31) / 32)        // transform blocks (item side)
#define TBU ((U_N + 31) / 32)        // transform blocks (user side)
#define CB  ((NMEMB + 255) / 256)    // count/fill blocks
#define NZ4 ((NKEYS + 4) / 4)        // int4 count for offs zeroing

typedef float f32x2 __attribute__((ext_vector_type(2)));

// round-to-nearest-even-ish bf16 pack of two floats -> uint (lo=a, hi=b)
__device__ inline unsigned int pack_bf16(float a, float b) {
    unsigned int ua = __float_as_uint(a);
    ua += 0x7FFFu + ((ua >> 16) & 1u);
    unsigned int ub = __float_as_uint(b);
    ub += 0x7FFFu + ((ub >> 16) & 1u);
    return (ua >> 16) | (ub & 0xFFFF0000u);
}

// ---------------------------------------------------------------------------
// Zero offs[] + two sentinel pairs past the end of pairs[].
// ---------------------------------------------------------------------------
__global__ __launch_bounds__(256) void zero_kernel(int4* __restrict__ offs4,
                                                   int2* __restrict__ sentinel)
{
    int t = blockIdx.x * 256 + threadIdx.x;
    if (t < NZ4) offs4[t] = make_int4(0, 0, 0, 0);
    if (t == 0) { sentinel[0] = make_int2(0, 0); sentinel[1] = make_int2(0, 0); }
}

// ---------------------------------------------------------------------------
// Fused INDEPENDENT work: transform role (tA = item_emb @ u_w bf16,
// tB = user_emb @ i_w bf16; W read from L2, no LDS so the count role keeps
// full occupancy) + count role (one membership per thread; atomic return
// value = rank within bucket).
// ---------------------------------------------------------------------------
__global__ __launch_bounds__(256) void work_kernel(
    const float* __restrict__ item_emb, const float* __restrict__ user_emb,
    const float* __restrict__ u_w, const float* __restrict__ i_w,
    unsigned int* __restrict__ tA, unsigned int* __restrict__ tB,
    const int* __restrict__ eu, const int* __restrict__ ei,
    int* __restrict__ offs, int* __restrict__ rank_u, int* __restrict__ rank_i)
{
    if (blockIdx.x >= TBI + TBU) {
        // ---- count role ----
        int t = (blockIdx.x - TBI - TBU) * 256 + threadIdx.x;
        if (t >= NMEMB) return;
        if (t < NEDGE) {
            int e = t;
            int key = eu[e] * 4 + e / E_N;
            rank_u[e] = atomicAdd(&offs[key], 1);
        } else {
            int e = t - NEDGE;
            int key = NKEYU + ei[e] * 4 + e / E_N;
            rank_i[e] = atomicAdd(&offs[key], 1);
        }
        return;
    }

    // ---- transform role ----
    const float* X; const float* W; unsigned int* Y; int N; int blk;
    if (blockIdx.x < TBI) {
        X = item_emb; W = u_w; Y = tA; N = I_N; blk = blockIdx.x;
    } else {
        X = user_emb; W = i_w; Y = tB; N = U_N; blk = blockIdx.x - TBI;
    }

    int rr = threadIdx.x & 31;
    int cg = threadIdx.x >> 5;
    int c0 = cg * 16;
    int r  = blk * 32 + rr;
    bool valid = (r < N);
    int rc = valid ? r : (N - 1);
    const float* xrow = X + (size_t)rc * D_N;

    float4 acc[4];
    #pragma unroll
    for (int c = 0; c < 4; ++c) acc[c] = make_float4(0.f, 0.f, 0.f, 0.f);

    for (int k4 = 0; k4 < D_N / 4; ++k4) {
        float4 a = *reinterpret_cast<const float4*>(xrow + k4 * 4);
        #pragma unroll
        for (int kk = 0; kk < 4; ++kk) {
            float ak = (kk == 0) ? a.x : (kk == 1) ? a.y : (kk == 2) ? a.z : a.w;
            const float* wrow = W + (size_t)(k4 * 4 + kk) * D_N + c0;
            #pragma unroll
            for (int c = 0; c < 4; ++c) {
                const float4 wv = *reinterpret_cast<const float4*>(wrow + c * 4);
                acc[c].x += ak * wv.x;
                acc[c].y += ak * wv.y;
                acc[c].z += ak * wv.z;
                acc[c].w += ak * wv.w;
            }
        }
    }
    if (valid) {
        unsigned int* yrow = Y + (size_t)r * (D_N / 2) + c0 / 2;
        #pragma unroll
        for (int c = 0; c < 4; ++c) {
            yrow[2 * c]     = pack_bf16(acc[c].x, acc[c].y);
            yrow[2 * c + 1] = pack_bf16(acc[c].z, acc[c].w);
        }
    }
}

// ---------------------------------------------------------------------------
// In-place hierarchical exclusive scan over offs[NKEYS].
// ---------------------------------------------------------------------------
__global__ __launch_bounds__(256) void scan1_kernel(
    int* __restrict__ offs, int* __restrict__ bsum)
{
    __shared__ int s[256];
    int base = blockIdx.x * SCHUNK + threadIdx.x * 8;
    int v[8]; int tsum = 0;
    #pragma unroll
    for (int j = 0; j < 8; ++j) {
        int idx = base + j;
        v[j] = (idx < NKEYS) ? offs[idx] : 0;
        tsum += v[j];
    }
    s[threadIdx.x] = tsum; __syncthreads();
    for (int off = 1; off < 256; off <<= 1) {
        int t = (threadIdx.x >= off) ? s[threadIdx.x - off] : 0;
        __syncthreads(); s[threadIdx.x] += t; __syncthreads();
    }
    int excl = s[threadIdx.x] - tsum;
    if (threadIdx.x == 255) bsum[blockIdx.x] = s[255];
    int run = excl;
    #pragma unroll
    for (int j = 0; j < 8; ++j) {
        int idx = base + j;
        if (idx < NKEYS) offs[idx] = run;
        run += v[j];
    }
}

__global__ __launch_bounds__(512) void scan2_kernel(int* __restrict__ bsum,
                                                    int* __restrict__ offs)
{
    __shared__ int s[512];
    int v = (threadIdx.x < SNBLK) ? bsum[threadIdx.x] : 0;
    s[threadIdx.x] = v; __syncthreads();
    for (int off = 1; off < 512; off <<= 1) {
        int t = (threadIdx.x >= off) ? s[threadIdx.x - off] : 0;
        __syncthreads(); s[threadIdx.x] += t; __syncthreads();
    }
    if (threadIdx.x < SNBLK) bsum[threadIdx.x] = s[threadIdx.x] - v;
    if (threadIdx.x == 511) offs[NKEYS] = s[511];
}

__global__ __launch_bounds__(256) void scan3_kernel(int* __restrict__ offs,
                                                    const int* __restrict__ bsum)
{
    int add = bsum[blockIdx.x];
    int base = blockIdx.x * SCHUNK + threadIdx.x * 8;
    #pragma unroll
    for (int j = 0; j < 8; ++j) {
        int idx = base + j;
        if (idx < NKEYS) offs[idx] += add;
    }
}

// ---------------------------------------------------------------------------
// Atomic-free fill: pos = offs[key] + precomputed rank.
// ---------------------------------------------------------------------------
__global__ __launch_bounds__(256) void fill_kernel(
    const int* __restrict__ eu, const int* __restrict__ ei,
    const float* __restrict__ ew,
    const int* __restrict__ offs,
    const int* __restrict__ rank_u, const int* __restrict__ rank_i,
    int2* __restrict__ pairs)
{
    int t = blockIdx.x * 256 + threadIdx.x;
    if (t >= NMEMB) return;
    if (t < NEDGE) {
        int e = t;
        int b = e / E_N;
        int key = eu[e] * 4 + b;
        int pos = offs[key] + rank_u[e];
        pairs[pos] = make_int2(ei[e], __float_as_int(ew[e]));
    } else {
        int e = t - NEDGE;
        int b = e / E_N;
        int key = NKEYU + ei[e] * 4 + b;
        int pos = offs[key] + rank_i[e];
        pairs[pos] = make_int2(eu[e], __float_as_int(ew[e]));
    }
}

// ---------------------------------------------------------------------------
// Fused gather: one wave per destination row; lane owns 2 dims (1 uint of
// 2 bf16). 4 behavior buckets advance in lockstep, x2-unrolled: 8
// memberships in flight per iteration (4 int4 pair loads + 8 T-row loads).
// All wave-uniform control pinned to SGPRs via readfirstlane. Dead slots
// clamp to a valid position with weight 0; sentinel pairs past NMEMB make
// tail int4 reads safe. NT stores keep L2/L3 for the bf16 row pool.
// ---------------------------------------------------------------------------
__global__ __launch_bounds__(256) void gather_kernel(
    const unsigned int* __restrict__ tA, const unsigned int* __restrict__ tB,
    const int2* __restrict__ pairs, const int* __restrict__ offs,
    float* __restrict__ single_u, float* __restrict__ multi_u,
    float* __restrict__ single_i, float* __restrict__ multi_i,
    const float* __restrict__ alpha_p)
{
    int rg = blockIdx.x * 4 + (threadIdx.x >> 6);
    if (rg >= U_N + I_N) return;
    bool uside = rg < U_N;
    int r = uside ? rg : rg - U_N;
    const unsigned int* T = uside ? tA : tB;
    float* single  = uside ? single_u : single_i;
    float* multi   = uside ? multi_u : multi_i;
    int N  = uside ? U_N : I_N;
    int k0 = uside ? r * 4 : NKEYU + r * 4;

    float alpha = alpha_p[0];
    int lane = threadIdx.x & 63;

    int o0 = __builtin_amdgcn_readfirstlane(offs[k0]);
    int o1 = __builtin_amdgcn_readfirstlane(offs[k0 + 1]);
    int o2 = __builtin_amdgcn_readfirstlane(offs[k0 + 2]);
    int o3 = __builtin_amdgcn_readfirstlane(offs[k0 + 3]);
    int o4 = __builtin_amdgcn_readfirstlane(offs[k0 + 4]);
    int p0 = o0, p1 = o1, p2 = o2, p3 = o3;

    float ax0 = 0.f, ay0 = 0.f, ax1 = 0.f, ay1 = 0.f;
    float ax2 = 0.f, ay2 = 0.f, ax3 = 0.f, ay3 = 0.f;

    while ((p0 < o1) | (p1 < o2) | (p2 < o3) | (p3 < o4)) {
        int a0 = p0 < o1, b0 = (p0 + 1) < o1;
        int a1 = p1 < o2, b1 = (p1 + 1) < o2;
        int a2 = p2 < o3, b2 = (p2 + 1) < o3;
        int a3 = p3 < o4, b3 = (p3 + 1) < o4;
        // clamp dead slots to a valid in-range position (o0 < NMEMB while
        // the loop is active); int4 reads pairs[i..i+1], sentinel-covered.
        int i0 = a0 ? p0 : o0;
        int i1 = a1 ? p1 : o0;
        int i2 = a2 ? p2 : o0;
        int i3 = a3 ? p3 : o0;
        int4 Q0 = *reinterpret_cast<const int4*>(pairs + i0);
        int4 Q1 = *reinterpret_cast<const int4*>(pairs + i1);
        int4 Q2 = *reinterpret_cast<const int4*>(pairs + i2);
        int4 Q3 = *reinterpret_cast<const int4*>(pairs + i3);
        int sx0a = __builtin_amdgcn_readfirstlane(Q0.x);
        int sw0a = __builtin_amdgcn_readfirstlane(Q0.y);
        int sx0b = __builtin_amdgcn_readfirstlane(Q0.z);
        int sw0b = __builtin_amdgcn_readfirstlane(Q0.w);
        int sx1a = __builtin_amdgcn_readfirstlane(Q1.x);
        int sw1a = __builtin_amdgcn_readfirstlane(Q1.y);
        int sx1b = __builtin_amdgcn_readfirstlane(Q1.z);
        int sw1b = __builtin_amdgcn_readfirstlane(Q1.w);
        int sx2a = __builtin_amdgcn_readfirstlane(Q2.x);
        int sw2a = __builtin_amdgcn_readfirstlane(Q2.y);
        int sx2b = __builtin_amdgcn_readfirstlane(Q2.z);
        int sw2b = __builtin_amdgcn_readfirstlane(Q2.w);
        int sx3a = __builtin_amdgcn_readfirstlane(Q3.x);
        int sw3a = __builtin_amdgcn_readfirstlane(Q3.y);
        int sx3b = __builtin_amdgcn_readfirstlane(Q3.z);
        int sw3b = __builtin_amdgcn_readfirstlane(Q3.w);
        unsigned int d0a = T[(size_t)sx0a * (D_N / 2) + lane];
        unsigned int d0b = T[(size_t)sx0b * (D_N / 2) + lane];
        unsigned int d1a = T[(size_t)sx1a * (D_N / 2) + lane];
        unsigned int d1b = T[(size_t)sx1b * (D_N / 2) + lane];
        unsigned int d2a = T[(size_t)sx2a * (D_N / 2) + lane];
        unsigned int d2b = T[(size_t)sx2b * (D_N / 2) + lane];
        unsigned int d3a = T[(size_t)sx3a * (D_N / 2) + lane];
        unsigned int d3b = T[(size_t)sx3b * (D_N / 2) + lane];
        float w0a = a0 ? __int_as_float(sw0a) : 0.f;
        float w0b = b0 ? __int_as_float(sw0b) : 0.f;
        float w1a = a1 ? __int_as_float(sw1a) : 0.f;
        float w1b = b1 ? __int_as_float(sw1b) : 0.f;
        float w2a = a2 ? __int_as_float(sw2a) : 0.f;
        float w2b = b2 ? __int_as_float(sw2b) : 0.f;
        float w3a = a3 ? __int_as_float(sw3a) : 0.f;
        float w3b = b3 ? __int_as_float(sw3b) : 0.f;
        ax0 += w0a * __uint_as_float(d0a << 16)
             + w0b * __uint_as_float(d0b << 16);
        ay0 += w0a * __uint_as_float(d0a & 0xFFFF0000u)
             + w0b * __uint_as_float(d0b & 0xFFFF0000u);
        ax1 += w1a * __uint_as_float(d1a << 16)
             + w1b * __uint_as_float(d1b << 16);
        ay1 += w1a * __uint_as_float(d1a & 0xFFFF0000u)
             + w1b * __uint_as_float(d1b & 0xFFFF0000u);
        ax2 += w2a * __uint_as_float(d2a << 16)
             + w2b * __uint_as_float(d2b << 16);
        ay2 += w2a * __uint_as_float(d2a & 0xFFFF0000u)
             + w2b * __uint_as_float(d2b & 0xFFFF0000u);
        ax3 += w3a * __uint_as_float(d3a << 16)
             + w3b * __uint_as_float(d3b << 16);
        ay3 += w3a * __uint_as_float(d3a & 0xFFFF0000u)
             + w3b * __uint_as_float(d3b & 0xFFFF0000u);
        p0 += a0 + b0; p1 += a1 + b1; p2 += a2 + b2; p3 += a3 + b3;
    }

    float mx = 0.25f * (ax0 + ax1 + ax2 + ax3);
    float my = 0.25f * (ay0 + ay1 + ay2 + ay3);

    f32x2 o;
    o.x = ax0 >= 0.f ? ax0 : alpha * ax0;
    o.y = ay0 >= 0.f ? ay0 : alpha * ay0;
    __builtin_nontemporal_store(o, reinterpret_cast<f32x2*>(
        single + ((size_t)0 * N + r) * D_N + lane * 2));
    o.x = ax1 >= 0.f ? ax1 : alpha * ax1;
    o.y = ay1 >= 0.f ? ay1 : alpha * ay1;
    __builtin_nontemporal_store(o, reinterpret_cast<f32x2*>(
        single + ((size_t)1 * N + r) * D_N + lane * 2));
    o.x = ax2 >= 0.f ? ax2 : alpha * ax2;
    o.y = ay2 >= 0.f ? ay2 : alpha * ay2;
    __builtin_nontemporal_store(o, reinterpret_cast<f32x2*>(
        single + ((size_t)2 * N + r) * D_N + lane * 2));
    o.x = ax3 >= 0.f ? ax3 : alpha * ax3;
    o.y = ay3 >= 0.f ? ay3 : alpha * ay3;
    __builtin_nontemporal_store(o, reinterpret_cast<f32x2*>(
        single + ((size_t)3 * N + r) * D_N + lane * 2));

    o.x = mx >= 0.f ? mx : alpha * mx;
    o.y = my >= 0.f ? my : alpha * my;
    __builtin_nontemporal_store(o, reinterpret_cast<f32x2*>(
        multi + (size_t)r * D_N + lane * 2));
}

extern "C" void kernel_launch(void* const* d_in, const int* in_sizes, int n_in,
                              void* d_out, int out_size, void* d_ws, size_t ws_size,
                              hipStream_t stream) {
    const float* user_emb = (const float*)d_in[0];
    const float* item_emb = (const float*)d_in[1];
    const int*   eu       = (const int*)d_in[2];
    const int*   ei       = (const int*)d_in[3];
    const float* ew       = (const float*)d_in[4];
    const float* u_w      = (const float*)d_in[5];
    const float* i_w      = (const float*)d_in[6];
    const float* alpha    = (const float*)d_in[7];

    float* out      = (float*)d_out;
    float* multi_u  = out;                                      // [U][D]
    float* multi_i  = out + (size_t)U_N * D_N;                  // [I][D]
    float* single_u = out + (size_t)(U_N + I_N) * D_N;          // [B][U][D]
    float* single_i = single_u + (size_t)B_N * U_N * D_N;       // [B][I][D]

    // ranks live in multi_i's slot (consumed by fill; gather writes after).
    int* rank_u = (int*)multi_i;                                // 8 MB
    int* rank_i = rank_u + NEDGE;                               // 8 MB

    // d_ws: offs | bsum | pairs(+2 sentinels) | tA(bf16) | tB(bf16) (~73 MB)
    int*  offs  = (int*)d_ws;                                   // NKEYS+4
    int*  bsum  = offs + (NKEYS + 4);                           // 512
    int2* pairs = (int2*)((char*)d_ws + ((((NKEYS + 4 + 512) * 4) + 255) & ~255));
    unsigned int* tA = (unsigned int*)(pairs + NMEMB + 2);      // [I][64] 12.8 MB
    unsigned int* tB = tA + (size_t)I_N * (D_N / 2);            // [U][64] 25.6 MB

    zero_kernel<<<(NZ4 + 255) / 256, 256, 0, stream>>>((int4*)offs,
                                                       pairs + NMEMB);
    work_kernel<<<TBI + TBU + CB, 256, 0, stream>>>(
        item_emb, user_emb, u_w, i_w, tA, tB, eu, ei, offs, rank_u, rank_i);
    scan1_kernel<<<SNBLK, 256, 0, stream>>>(offs, bsum);
    scan2_kernel<<<1, 512, 0, stream>>>(bsum, offs);
    scan3_kernel<<<SNBLK, 256, 0, stream>>>(offs, bsum);
    fill_kernel<<<CB, 256, 0, stream>>>(eu, ei, ew, offs,
                                        rank_u, rank_i, pairs);
    gather_kernel<<<(U_N + I_N + 3) / 4, 256, 0, stream>>>(
        tA, tB, pairs, offs,
        single_u, multi_u, single_i, multi_i, alpha);
}

// Round 13
// 600.095 us; speedup vs baseline: 1.2532x; 1.2532x over previous
//
#include <hip/hip_runtime.h>

#define U_N 100000
#define I_N 50000
#define D_N 128
#define B_N 4
#define E_N 500000
#define NEDGE (B_N * E_N)            // 2,000,000
#define NKEYU (4 * U_N)              // keys u*4+b
#define NKEYS (NKEYU + 4 * I_N)      // 600,000
#define NMEMB (2 * NEDGE)            // 4,000,000
#define SCHUNK 2048
#define SNBLK ((NKEYS + SCHUNK - 1) / SCHUNK)   // 293
#define TBI ((I_N + 31) / 32)        // transform blocks (item side)
#define TBU ((U_N + 31) / 32)        // transform blocks (user side)
#define CB  ((NMEMB + 255) / 256)    // count/fill blocks
#define NZ4 ((NKEYS + 4) / 4)        // int4 count for offs zeroing
#define ZB  ((NZ4 + 255) / 256)      // zero-role blocks

typedef float f32x2 __attribute__((ext_vector_type(2)));

// round-to-nearest-even-ish bf16 pack of two floats -> uint (lo=a, hi=b)
__device__ inline unsigned int pack_bf16(float a, float b) {
    unsigned int ua = __float_as_uint(a);
    ua += 0x7FFFu + ((ua >> 16) & 1u);
    unsigned int ub = __float_as_uint(b);
    ub += 0x7FFFu + ((ub >> 16) & 1u);
    return (ua >> 16) | (ub & 0xFFFF0000u);
}

// ---------------------------------------------------------------------------
// Fused: tA = item_emb @ u_w (bf16), tB = user_emb @ i_w (bf16) with
// LDS-staged W, plus zero-role blocks clearing offs[] and the sentinels.
// ---------------------------------------------------------------------------
__global__ __launch_bounds__(256) void transform2_kernel(
    const float* __restrict__ item_emb, const float* __restrict__ user_emb,
    const float* __restrict__ u_w, const float* __restrict__ i_w,
    unsigned int* __restrict__ tA, unsigned int* __restrict__ tB,
    int4* __restrict__ offs4, int2* __restrict__ sentinel)
{
    __shared__ float wlds[D_N][D_N];

    const float* X; const float* W; unsigned int* Y; int N; int blk;
    if (blockIdx.x < TBI) {
        X = item_emb; W = u_w; Y = tA; N = I_N; blk = blockIdx.x;
    } else if (blockIdx.x < TBI + TBU) {
        X = user_emb; W = i_w; Y = tB; N = U_N; blk = blockIdx.x - TBI;
    } else {
        int t = (blockIdx.x - TBI - TBU) * 256 + threadIdx.x;
        if (t < NZ4) offs4[t] = make_int4(0, 0, 0, 0);
        if (t == 0) { sentinel[0] = make_int2(0, 0); sentinel[1] = make_int2(0, 0); }
        return;
    }

    for (int idx = threadIdx.x; idx < D_N * D_N / 4; idx += 256)
        reinterpret_cast<float4*>(&wlds[0][0])[idx] =
            reinterpret_cast<const float4*>(W)[idx];
    __syncthreads();

    int rr = threadIdx.x & 31;
    int cg = threadIdx.x >> 5;
    int c0 = cg * 16;
    int r  = blk * 32 + rr;
    bool valid = (r < N);
    int rc = valid ? r : (N - 1);
    const float* xrow = X + (size_t)rc * D_N;

    float4 acc[4];
    #pragma unroll
    for (int c = 0; c < 4; ++c) acc[c] = make_float4(0.f, 0.f, 0.f, 0.f);

    for (int k4 = 0; k4 < D_N / 4; ++k4) {
        float4 a = *reinterpret_cast<const float4*>(xrow + k4 * 4);
        #pragma unroll
        for (int kk = 0; kk < 4; ++kk) {
            float ak = (kk == 0) ? a.x : (kk == 1) ? a.y : (kk == 2) ? a.z : a.w;
            #pragma unroll
            for (int c = 0; c < 4; ++c) {
                const float4 wv = *reinterpret_cast<const float4*>(
                    &wlds[k4 * 4 + kk][c0 + c * 4]);
                acc[c].x += ak * wv.x;
                acc[c].y += ak * wv.y;
                acc[c].z += ak * wv.z;
                acc[c].w += ak * wv.w;
            }
        }
    }
    if (valid) {
        unsigned int* yrow = Y + (size_t)r * (D_N / 2) + c0 / 2;
        #pragma unroll
        for (int c = 0; c < 4; ++c) {
            yrow[2 * c]     = pack_bf16(acc[c].x, acc[c].y);
            yrow[2 * c + 1] = pack_bf16(acc[c].z, acc[c].w);
        }
    }
}

// ---------------------------------------------------------------------------
// Count + rank: one membership per thread; atomic return value = rank.
// ---------------------------------------------------------------------------
__global__ __launch_bounds__(256) void count_kernel(
    const int* __restrict__ eu, const int* __restrict__ ei,
    int* __restrict__ offs, int* __restrict__ rank_u, int* __restrict__ rank_i)
{
    int t = blockIdx.x * 256 + threadIdx.x;
    if (t >= NMEMB) return;
    if (t < NEDGE) {
        int e = t;
        int key = eu[e] * 4 + e / E_N;
        rank_u[e] = atomicAdd(&offs[key], 1);
    } else {
        int e = t - NEDGE;
        int key = NKEYU + ei[e] * 4 + e / E_N;
        rank_i[e] = atomicAdd(&offs[key], 1);
    }
}

// ---------------------------------------------------------------------------
// In-place hierarchical exclusive scan over offs[NKEYS].
// ---------------------------------------------------------------------------
__global__ __launch_bounds__(256) void scan1_kernel(
    int* __restrict__ offs, int* __restrict__ bsum)
{
    __shared__ int s[256];
    int base = blockIdx.x * SCHUNK + threadIdx.x * 8;
    int v[8]; int tsum = 0;
    #pragma unroll
    for (int j = 0; j < 8; ++j) {
        int idx = base + j;
        v[j] = (idx < NKEYS) ? offs[idx] : 0;
        tsum += v[j];
    }
    s[threadIdx.x] = tsum; __syncthreads();
    for (int off = 1; off < 256; off <<= 1) {
        int t = (threadIdx.x >= off) ? s[threadIdx.x - off] : 0;
        __syncthreads(); s[threadIdx.x] += t; __syncthreads();
    }
    int excl = s[threadIdx.x] - tsum;
    if (threadIdx.x == 255) bsum[blockIdx.x] = s[255];
    int run = excl;
    #pragma unroll
    for (int j = 0; j < 8; ++j) {
        int idx = base + j;
        if (idx < NKEYS) offs[idx] = run;
        run += v[j];
    }
}

__global__ __launch_bounds__(512) void scan2_kernel(int* __restrict__ bsum,
                                                    int* __restrict__ offs)
{
    __shared__ int s[512];
    int v = (threadIdx.x < SNBLK) ? bsum[threadIdx.x] : 0;
    s[threadIdx.x] = v; __syncthreads();
    for (int off = 1; off < 512; off <<= 1) {
        int t = (threadIdx.x >= off) ? s[threadIdx.x - off] : 0;
        __syncthreads(); s[threadIdx.x] += t; __syncthreads();
    }
    if (threadIdx.x < SNBLK) bsum[threadIdx.x] = s[threadIdx.x] - v;
    if (threadIdx.x == 511) offs[NKEYS] = s[511];
}

__global__ __launch_bounds__(256) void scan3_kernel(int* __restrict__ offs,
                                                    const int* __restrict__ bsum)
{
    int add = bsum[blockIdx.x];
    int base = blockIdx.x * SCHUNK + threadIdx.x * 8;
    #pragma unroll
    for (int j = 0; j < 8; ++j) {
        int idx = base + j;
        if (idx < NKEYS) offs[idx] += add;
    }
}

// ---------------------------------------------------------------------------
// Atomic-free fill: pos = offs[key] + precomputed rank.
// ---------------------------------------------------------------------------
__global__ __launch_bounds__(256) void fill_kernel(
    const int* __restrict__ eu, const int* __restrict__ ei,
    const float* __restrict__ ew,
    const int* __restrict__ offs,
    const int* __restrict__ rank_u, const int* __restrict__ rank_i,
    int2* __restrict__ pairs)
{
    int t = blockIdx.x * 256 + threadIdx.x;
    if (t >= NMEMB) return;
    if (t < NEDGE) {
        int e = t;
        int b = e / E_N;
        int key = eu[e] * 4 + b;
        int pos = offs[key] + rank_u[e];
        pairs[pos] = make_int2(ei[e], __float_as_int(ew[e]));
    } else {
        int e = t - NEDGE;
        int b = e / E_N;
        int key = NKEYU + ei[e] * 4 + b;
        int pos = offs[key] + rank_i[e];
        pairs[pos] = make_int2(eu[e], __float_as_int(ew[e]));
    }
}

// ---------------------------------------------------------------------------
// Fused gather: one wave per destination row; lane owns 2 dims (1 uint of
// 2 bf16). 4 behavior buckets advance in lockstep, x2-unrolled: 8
// memberships in flight per iteration (4 int4 pair loads + 8 T-row loads).
// All wave-uniform control pinned to SGPRs via readfirstlane. Dead slots
// clamp to a valid position with weight 0; sentinel pairs past NMEMB make
// tail int4 reads safe. NT stores keep L2/L3 for the bf16 row pool.
// ---------------------------------------------------------------------------
__global__ __launch_bounds__(256) void gather_kernel(
    const unsigned int* __restrict__ tA, const unsigned int* __restrict__ tB,
    const int2* __restrict__ pairs, const int* __restrict__ offs,
    float* __restrict__ single_u, float* __restrict__ multi_u,
    float* __restrict__ single_i, float* __restrict__ multi_i,
    const float* __restrict__ alpha_p)
{
    int rg = blockIdx.x * 4 + (threadIdx.x >> 6);
    if (rg >= U_N + I_N) return;
    bool uside = rg < U_N;
    int r = uside ? rg : rg - U_N;
    const unsigned int* T = uside ? tA : tB;
    float* single  = uside ? single_u : single_i;
    float* multi   = uside ? multi_u : multi_i;
    int N  = uside ? U_N : I_N;
    int k0 = uside ? r * 4 : NKEYU + r * 4;

    float alpha = alpha_p[0];
    int lane = threadIdx.x & 63;

    int o0 = __builtin_amdgcn_readfirstlane(offs[k0]);
    int o1 = __builtin_amdgcn_readfirstlane(offs[k0 + 1]);
    int o2 = __builtin_amdgcn_readfirstlane(offs[k0 + 2]);
    int o3 = __builtin_amdgcn_readfirstlane(offs[k0 + 3]);
    int o4 = __builtin_amdgcn_readfirstlane(offs[k0 + 4]);
    int p0 = o0, p1 = o1, p2 = o2, p3 = o3;

    float ax0 = 0.f, ay0 = 0.f, ax1 = 0.f, ay1 = 0.f;
    float ax2 = 0.f, ay2 = 0.f, ax3 = 0.f, ay3 = 0.f;

    while ((p0 < o1) | (p1 < o2) | (p2 < o3) | (p3 < o4)) {
        int a0 = p0 < o1, b0 = (p0 + 1) < o1;
        int a1 = p1 < o2, b1 = (p1 + 1) < o2;
        int a2 = p2 < o3, b2 = (p2 + 1) < o3;
        int a3 = p3 < o4, b3 = (p3 + 1) < o4;
        int i0 = a0 ? p0 : o0;
        int i1 = a1 ? p1 : o0;
        int i2 = a2 ? p2 : o0;
        int i3 = a3 ? p3 : o0;
        int4 Q0 = *reinterpret_cast<const int4*>(pairs + i0);
        int4 Q1 = *reinterpret_cast<const int4*>(pairs + i1);
        int4 Q2 = *reinterpret_cast<const int4*>(pairs + i2);
        int4 Q3 = *reinterpret_cast<const int4*>(pairs + i3);
        int sx0a = __builtin_amdgcn_readfirstlane(Q0.x);
        int sw0a = __builtin_amdgcn_readfirstlane(Q0.y);
        int sx0b = __builtin_amdgcn_readfirstlane(Q0.z);
        int sw0b = __builtin_amdgcn_readfirstlane(Q0.w);
        int sx1a = __builtin_amdgcn_readfirstlane(Q1.x);
        int sw1a = __builtin_amdgcn_readfirstlane(Q1.y);
        int sx1b = __builtin_amdgcn_readfirstlane(Q1.z);
        int sw1b = __builtin_amdgcn_readfirstlane(Q1.w);
        int sx2a = __builtin_amdgcn_readfirstlane(Q2.x);
        int sw2a = __builtin_amdgcn_readfirstlane(Q2.y);
        int sx2b = __builtin_amdgcn_readfirstlane(Q2.z);
        int sw2b = __builtin_amdgcn_readfirstlane(Q2.w);
        int sx3a = __builtin_amdgcn_readfirstlane(Q3.x);
        int sw3a = __builtin_amdgcn_readfirstlane(Q3.y);
        int sx3b = __builtin_amdgcn_readfirstlane(Q3.z);
        int sw3b = __builtin_amdgcn_readfirstlane(Q3.w);
        unsigned int d0a = T[(size_t)sx0a * (D_N / 2) + lane];
        unsigned int d0b = T[(size_t)sx0b * (D_N / 2) + lane];
        unsigned int d1a = T[(size_t)sx1a * (D_N / 2) + lane];
        unsigned int d1b = T[(size_t)sx1b * (D_N / 2) + lane];
        unsigned int d2a = T[(size_t)sx2a * (D_N / 2) + lane];
        unsigned int d2b = T[(size_t)sx2b * (D_N / 2) + lane];
        unsigned int d3a = T[(size_t)sx3a * (D_N / 2) + lane];
        unsigned int d3b = T[(size_t)sx3b * (D_N / 2) + lane];
        float w0a = a0 ? __int_as_float(sw0a) : 0.f;
        float w0b = b0 ? __int_as_float(sw0b) : 0.f;
        float w1a = a1 ? __int_as_float(sw1a) : 0.f;
        float w1b = b1 ? __int_as_float(sw1b) : 0.f;
        float w2a = a2 ? __int_as_float(sw2a) : 0.f;
        float w2b = b2 ? __int_as_float(sw2b) : 0.f;
        float w3a = a3 ? __int_as_float(sw3a) : 0.f;
        float w3b = b3 ? __int_as_float(sw3b) : 0.f;
        ax0 += w0a * __uint_as_float(d0a << 16)
             + w0b * __uint_as_float(d0b << 16);
        ay0 += w0a * __uint_as_float(d0a & 0xFFFF0000u)
             + w0b * __uint_as_float(d0b & 0xFFFF0000u);
        ax1 += w1a * __uint_as_float(d1a << 16)
             + w1b * __uint_as_float(d1b << 16);
        ay1 += w1a * __uint_as_float(d1a & 0xFFFF0000u)
             + w1b * __uint_as_float(d1b & 0xFFFF0000u);
        ax2 += w2a * __uint_as_float(d2a << 16)
             + w2b * __uint_as_float(d2b << 16);
        ay2 += w2a * __uint_as_float(d2a & 0xFFFF0000u)
             + w2b * __uint_as_float(d2b & 0xFFFF0000u);
        ax3 += w3a * __uint_as_float(d3a << 16)
             + w3b * __uint_as_float(d3b << 16);
        ay3 += w3a * __uint_as_float(d3a & 0xFFFF0000u)
             + w3b * __uint_as_float(d3b & 0xFFFF0000u);
        p0 += a0 + b0; p1 += a1 + b1; p2 += a2 + b2; p3 += a3 + b3;
    }

    float mx = 0.25f * (ax0 + ax1 + ax2 + ax3);
    float my = 0.25f * (ay0 + ay1 + ay2 + ay3);

    f32x2 o;
    o.x = ax0 >= 0.f ? ax0 : alpha * ax0;
    o.y = ay0 >= 0.f ? ay0 : alpha * ay0;
    __builtin_nontemporal_store(o, reinterpret_cast<f32x2*>(
        single + ((size_t)0 * N + r) * D_N + lane * 2));
    o.x = ax1 >= 0.f ? ax1 : alpha * ax1;
    o.y = ay1 >= 0.f ? ay1 : alpha * ay1;
    __builtin_nontemporal_store(o, reinterpret_cast<f32x2*>(
        single + ((size_t)1 * N + r) * D_N + lane * 2));
    o.x = ax2 >= 0.f ? ax2 : alpha * ax2;
    o.y = ay2 >= 0.f ? ay2 : alpha * ay2;
    __builtin_nontemporal_store(o, reinterpret_cast<f32x2*>(
        single + ((size_t)2 * N + r) * D_N + lane * 2));
    o.x = ax3 >= 0.f ? ax3 : alpha * ax3;
    o.y = ay3 >= 0.f ? ay3 : alpha * ay3;
    __builtin_nontemporal_store(o, reinterpret_cast<f32x2*>(
        single + ((size_t)3 * N + r) * D_N + lane * 2));

    o.x = mx >= 0.f ? mx : alpha * mx;
    o.y = my >= 0.f ? my : alpha * my;
    __builtin_nontemporal_store(o, reinterpret_cast<f32x2*>(
        multi + (size_t)r * D_N + lane * 2));
}

extern "C" void kernel_launch(void* const* d_in, const int* in_sizes, int n_in,
                              void* d_out, int out_size, void* d_ws, size_t ws_size,
                              hipStream_t stream) {
    const float* user_emb = (const float*)d_in[0];
    const float* item_emb = (const float*)d_in[1];
    const int*   eu       = (const int*)d_in[2];
    const int*   ei       = (const int*)d_in[3];
    const float* ew       = (const float*)d_in[4];
    const float* u_w      = (const float*)d_in[5];
    const float* i_w      = (const float*)d_in[6];
    const float* alpha    = (const float*)d_in[7];

    float* out      = (float*)d_out;
    float* multi_u  = out;                                      // [U][D]
    float* multi_i  = out + (size_t)U_N * D_N;                  // [I][D]
    float* single_u = out + (size_t)(U_N + I_N) * D_N;          // [B][U][D]
    float* single_i = single_u + (size_t)B_N * U_N * D_N;       // [B][I][D]

    // ranks live in multi_i's slot (consumed by fill; gather writes after).
    int* rank_u = (int*)multi_i;                                // 8 MB
    int* rank_i = rank_u + NEDGE;                               // 8 MB

    // d_ws: offs | bsum | pairs(+2 sentinels) | tA(bf16) | tB(bf16) (~73 MB)
    int*  offs  = (int*)d_ws;                                   // NKEYS+4
    int*  bsum  = offs + (NKEYS + 4);                           // 512
    int2* pairs = (int2*)((char*)d_ws + ((((NKEYS + 4 + 512) * 4) + 255) & ~255));
    unsigned int* tA = (unsigned int*)(pairs + NMEMB + 2);      // [I][64] 12.8 MB
    unsigned int* tB = tA + (size_t)I_N * (D_N / 2);            // [U][64] 25.6 MB

    transform2_kernel<<<TBI + TBU + ZB, 256, 0, stream>>>(
        item_emb, user_emb, u_w, i_w, tA, tB, (int4*)offs, pairs + NMEMB);
    count_kernel<<<CB, 256, 0, stream>>>(eu, ei, offs, rank_u, rank_i);
    scan1_kernel<<<SNBLK, 256, 0, stream>>>(offs, bsum);
    scan2_kernel<<<1, 512, 0, stream>>>(bsum, offs);
    scan3_kernel<<<SNBLK, 256, 0, stream>>>(offs, bsum);
    fill_kernel<<<CB, 256, 0, stream>>>(eu, ei, ew, offs,
                                        rank_u, rank_i, pairs);
    gather_kernel<<<(U_N + I_N + 3) / 4, 256, 0, stream>>>(
        tA, tB, pairs, offs,
        single_u, multi_u, single_i, multi_i, alpha);
}